// Round 1
// baseline (372.786 us; speedup 1.0000x reference)
//
#include <hip/hip_runtime.h>
#include <math.h>

#define IMG_H 768
#define IMG_W 768
#define BATCH 16
#define TW 64
#define TH 16
#define HALO_W (TW + 2)            // 66
#define HALO_H (TH + 2)            // 18
#define HALO_N (HALO_W * HALO_H)   // 1188
#define NPIX ((size_t)BATCH * IMG_H * IMG_W)  // 9437184

// sobel at output pixel (y,x) of the tile; t points to an image's halo tile.
// Cross-correlation, zero (SAME) padding handled at load time.
__device__ __forceinline__ float sobel3(const float (*t)[HALO_W], int y, int x) {
    float a00 = t[y][x],     a01 = t[y][x + 1],     a02 = t[y][x + 2];
    float a10 = t[y + 1][x],                        a12 = t[y + 1][x + 2];
    float a20 = t[y + 2][x], a21 = t[y + 2][x + 1], a22 = t[y + 2][x + 2];
    // KX = [[-1,0,1],[-2,0,2],[-1,0,1]]
    float gx = (a02 - a00) + 2.f * (a12 - a10) + (a22 - a20);
    // KY = [[1,2,1],[0,0,0],[-1,-2,-1]]
    float gy = (a00 - a20) + 2.f * (a01 - a21) + (a02 - a22);
    return fabsf(gx) + fabsf(gy);
}

__global__ void zero_ws_kernel(float* acc) {
    if (threadIdx.x < 3) acc[threadIdx.x] = 0.f;
}

__global__ __launch_bounds__(256) void sobel_loss_main(
    const float* __restrict__ vis, const float* __restrict__ ir,
    const float* __restrict__ X, const float* __restrict__ Y,
    float* __restrict__ acc)
{
    __shared__ float s[4][HALO_H][HALO_W];
    __shared__ float red[3][4];

    const int tid = threadIdx.x;
    const int tx0 = blockIdx.x * TW;
    const int ty0 = blockIdx.y * TH;
    const size_t base = (size_t)blockIdx.z * (IMG_H * IMG_W);

    const float* i0 = vis + base;
    const float* i1 = ir + base;
    const float* i2 = X + base;
    const float* i3 = Y + base;

    // Stage halo tiles of all 4 images into LDS (zero padding outside image).
    for (int i = tid; i < HALO_N; i += 256) {
        int y = i / HALO_W;
        int x = i - y * HALO_W;
        int gy = ty0 + y - 1;
        int gx = tx0 + x - 1;
        bool inb = (gy >= 0) & (gy < IMG_H) & (gx >= 0) & (gx < IMG_W);
        int gidx = inb ? (gy * IMG_W + gx) : 0;
        float v0 = inb ? i0[gidx] : 0.f;
        float v1 = inb ? i1[gidx] : 0.f;
        float v2 = inb ? i2[gidx] : 0.f;
        float v3 = inb ? i3[gidx] : 0.f;
        s[0][y][x] = v0;
        s[1][y][x] = v1;
        s[2][y][x] = v2;
        s[3][y][x] = v3;
    }
    __syncthreads();

    float sX2 = 0.f, sY2 = 0.f, sL1 = 0.f;
    #pragma unroll
    for (int k = 0; k < (TW * TH) / 256; ++k) {
        int p = k * 256 + tid;
        int y = p >> 6;   // / TW
        int x = p & 63;   // % TW
        float gv = sobel3(s[0], y, x);
        float gi = sobel3(s[1], y, x);
        float gX = sobel3(s[2], y, x);
        float gY = sobel3(s[3], y, x);
        sX2 += gX * gX;
        sY2 += gY * gY;
        float j = fmaxf(gv, gi);
        sL1 += fabsf(gX - j);
    }

    // Wave (64-lane) reduction, then cross-wave via LDS.
    #pragma unroll
    for (int off = 32; off > 0; off >>= 1) {
        sX2 += __shfl_down(sX2, off);
        sY2 += __shfl_down(sY2, off);
        sL1 += __shfl_down(sL1, off);
    }
    int wave = tid >> 6;
    int lane = tid & 63;
    if (lane == 0) {
        red[0][wave] = sX2;
        red[1][wave] = sY2;
        red[2][wave] = sL1;
    }
    __syncthreads();
    if (tid == 0) {
        float a = red[0][0] + red[0][1] + red[0][2] + red[0][3];
        float b = red[1][0] + red[1][1] + red[1][2] + red[1][3];
        float c = red[2][0] + red[2][1] + red[2][2] + red[2][3];
        atomicAdd(&acc[0], a);
        atomicAdd(&acc[1], b);
        atomicAdd(&acc[2], c);
    }
}

__global__ void finalize_kernel(const float* __restrict__ acc, float* __restrict__ out) {
    if (threadIdx.x == 0) {
        out[0] = acc[1] / acc[0];                       // loss_in = sumY2 / sumX2
        out[1] = acc[2] * (1.f / (float)NPIX);          // loss_grad = sumL1 / N
    }
}

extern "C" void kernel_launch(void* const* d_in, const int* in_sizes, int n_in,
                              void* d_out, int out_size, void* d_ws, size_t ws_size,
                              hipStream_t stream) {
    const float* vis = (const float*)d_in[0];
    const float* ir  = (const float*)d_in[1];
    const float* X   = (const float*)d_in[2];
    const float* Y   = (const float*)d_in[3];
    float* out = (float*)d_out;
    float* acc = (float*)d_ws;

    zero_ws_kernel<<<1, 64, 0, stream>>>(acc);

    dim3 grid(IMG_W / TW, IMG_H / TH, BATCH);   // 12 x 48 x 16 = 9216 blocks
    sobel_loss_main<<<grid, 256, 0, stream>>>(vis, ir, X, Y, acc);

    finalize_kernel<<<1, 64, 0, stream>>>(acc, out);
}

// Round 2
// 59.544 us; speedup vs baseline: 6.2607x; 6.2607x over previous
//
#include <hip/hip_runtime.h>
#include <math.h>

#define IMG_H 768
#define IMG_W 768
#define BATCH 16
#define TW 64
#define TH 16
#define HALO_W (TW + 2)            // 66
#define HALO_H (TH + 2)            // 18
#define HALO_N (HALO_W * HALO_H)   // 1188
#define NBX (IMG_W / TW)           // 12
#define NBY (IMG_H / TH)           // 48
#define NBLOCKS (NBX * NBY * BATCH)  // 9216
#define NPIX ((size_t)BATCH * IMG_H * IMG_W)  // 9437184

// sobel at output pixel (y,x) of the tile; t points to an image's halo tile.
__device__ __forceinline__ float sobel3(const float (*t)[HALO_W], int y, int x) {
    float a00 = t[y][x],     a01 = t[y][x + 1],     a02 = t[y][x + 2];
    float a10 = t[y + 1][x],                        a12 = t[y + 1][x + 2];
    float a20 = t[y + 2][x], a21 = t[y + 2][x + 1], a22 = t[y + 2][x + 2];
    float gx = (a02 - a00) + 2.f * (a12 - a10) + (a22 - a20);
    float gy = (a00 - a20) + 2.f * (a01 - a21) + (a02 - a22);
    return fabsf(gx) + fabsf(gy);
}

__global__ __launch_bounds__(256) void sobel_loss_main(
    const float* __restrict__ vis, const float* __restrict__ ir,
    const float* __restrict__ X, const float* __restrict__ Y,
    float* __restrict__ part)   // part: [3][NBLOCKS]
{
    __shared__ float s[4][HALO_H][HALO_W];
    __shared__ float red[3][4];

    const int tid = threadIdx.x;
    const int tx0 = blockIdx.x * TW;
    const int ty0 = blockIdx.y * TH;
    const size_t base = (size_t)blockIdx.z * (IMG_H * IMG_W);
    const int bid = (blockIdx.z * NBY + blockIdx.y) * NBX + blockIdx.x;

    const float* i0 = vis + base;
    const float* i1 = ir + base;
    const float* i2 = X + base;
    const float* i3 = Y + base;

    for (int i = tid; i < HALO_N; i += 256) {
        int y = i / HALO_W;
        int x = i - y * HALO_W;
        int gy = ty0 + y - 1;
        int gx = tx0 + x - 1;
        bool inb = (gy >= 0) & (gy < IMG_H) & (gx >= 0) & (gx < IMG_W);
        int gidx = inb ? (gy * IMG_W + gx) : 0;
        float v0 = inb ? i0[gidx] : 0.f;
        float v1 = inb ? i1[gidx] : 0.f;
        float v2 = inb ? i2[gidx] : 0.f;
        float v3 = inb ? i3[gidx] : 0.f;
        s[0][y][x] = v0;
        s[1][y][x] = v1;
        s[2][y][x] = v2;
        s[3][y][x] = v3;
    }
    __syncthreads();

    float sX2 = 0.f, sY2 = 0.f, sL1 = 0.f;
    #pragma unroll
    for (int k = 0; k < (TW * TH) / 256; ++k) {
        int p = k * 256 + tid;
        int y = p >> 6;
        int x = p & 63;
        float gv = sobel3(s[0], y, x);
        float gi = sobel3(s[1], y, x);
        float gX = sobel3(s[2], y, x);
        float gY = sobel3(s[3], y, x);
        sX2 += gX * gX;
        sY2 += gY * gY;
        float j = fmaxf(gv, gi);
        sL1 += fabsf(gX - j);
    }

    #pragma unroll
    for (int off = 32; off > 0; off >>= 1) {
        sX2 += __shfl_down(sX2, off);
        sY2 += __shfl_down(sY2, off);
        sL1 += __shfl_down(sL1, off);
    }
    int wave = tid >> 6;
    int lane = tid & 63;
    if (lane == 0) {
        red[0][wave] = sX2;
        red[1][wave] = sY2;
        red[2][wave] = sL1;
    }
    __syncthreads();
    if (tid == 0) {
        part[0 * NBLOCKS + bid] = red[0][0] + red[0][1] + red[0][2] + red[0][3];
        part[1 * NBLOCKS + bid] = red[1][0] + red[1][1] + red[1][2] + red[1][3];
        part[2 * NBLOCKS + bid] = red[2][0] + red[2][1] + red[2][2] + red[2][3];
    }
}

__global__ __launch_bounds__(1024) void reduce_finalize(
    const float* __restrict__ part, float* __restrict__ out)
{
    __shared__ float red[3][16];
    const int tid = threadIdx.x;

    float a = 0.f, b = 0.f, c = 0.f;
    for (int i = tid; i < NBLOCKS; i += 1024) {
        a += part[0 * NBLOCKS + i];
        b += part[1 * NBLOCKS + i];
        c += part[2 * NBLOCKS + i];
    }
    #pragma unroll
    for (int off = 32; off > 0; off >>= 1) {
        a += __shfl_down(a, off);
        b += __shfl_down(b, off);
        c += __shfl_down(c, off);
    }
    int wave = tid >> 6;
    int lane = tid & 63;
    if (lane == 0) { red[0][wave] = a; red[1][wave] = b; red[2][wave] = c; }
    __syncthreads();
    if (tid == 0) {
        float sa = 0.f, sb = 0.f, sc = 0.f;
        #pragma unroll
        for (int w = 0; w < 16; ++w) { sa += red[0][w]; sb += red[1][w]; sc += red[2][w]; }
        out[0] = sb / sa;                      // loss_in = sumY2 / sumX2
        out[1] = sc * (1.f / (float)NPIX);     // loss_grad = sumL1 / N
    }
}

extern "C" void kernel_launch(void* const* d_in, const int* in_sizes, int n_in,
                              void* d_out, int out_size, void* d_ws, size_t ws_size,
                              hipStream_t stream) {
    const float* vis = (const float*)d_in[0];
    const float* ir  = (const float*)d_in[1];
    const float* X   = (const float*)d_in[2];
    const float* Y   = (const float*)d_in[3];
    float* out = (float*)d_out;
    float* part = (float*)d_ws;   // 3 * NBLOCKS floats = 110 KB

    dim3 grid(NBX, NBY, BATCH);   // 9216 blocks
    sobel_loss_main<<<grid, 256, 0, stream>>>(vis, ir, X, Y, part);
    reduce_finalize<<<1, 1024, 0, stream>>>(part, out);
}

// Round 3
// 47.987 us; speedup vs baseline: 7.7685x; 1.2408x over previous
//
#include <hip/hip_runtime.h>
#include <math.h>

#define IMG_H 768
#define IMG_W 768
#define BATCH 16
#define TH 12                      // output rows per block
#define TPB 192                    // threads per block = 768/4 (3 waves)
#define NSTRIPS (IMG_H / TH)       // 64
#define NBLOCKS (NSTRIPS * BATCH)  // 1024
#define NPIX ((size_t)BATCH * IMG_H * IMG_W)  // 9437184

struct Row6 { float v[6]; };       // x0-1 .. x0+4

__device__ __forceinline__ Row6 load_row(const float* __restrict__ img, int row, int x0) {
    Row6 r;
    if (row < 0 || row >= IMG_H) {
        #pragma unroll
        for (int i = 0; i < 6; ++i) r.v[i] = 0.f;
        return r;
    }
    const float* p = img + row * IMG_W + x0;
    float4 m = *(const float4*)p;                 // 16B-aligned (x0 % 4 == 0)
    r.v[0] = (x0 > 0) ? p[-1] : 0.f;
    r.v[1] = m.x; r.v[2] = m.y; r.v[3] = m.z; r.v[4] = m.w;
    r.v[5] = (x0 + 4 < IMG_W) ? p[4] : 0.f;
    return r;
}

// sobel |gx|+|gy| at output offset j (0..3) from 3 register rows
__device__ __forceinline__ float sob(const Row6& r0, const Row6& r1, const Row6& r2, int j) {
    float gx = (r0.v[j + 2] - r0.v[j]) + 2.f * (r1.v[j + 2] - r1.v[j]) + (r2.v[j + 2] - r2.v[j]);
    float gy = (r0.v[j] - r2.v[j]) + 2.f * (r0.v[j + 1] - r2.v[j + 1]) + (r0.v[j + 2] - r2.v[j + 2]);
    return fabsf(gx) + fabsf(gy);
}

__global__ __launch_bounds__(TPB) void sobel_loss_main(
    const float* __restrict__ vis, const float* __restrict__ ir,
    const float* __restrict__ X, const float* __restrict__ Y,
    float* __restrict__ part)   // part: [3][NBLOCKS]
{
    __shared__ float red[3][3];

    const int tid = threadIdx.x;
    const int x0 = tid * 4;
    const int y0 = blockIdx.x * TH;
    const size_t base = (size_t)blockIdx.y * (IMG_H * IMG_W);
    const int bid = blockIdx.y * NSTRIPS + blockIdx.x;

    const float* i0 = vis + base;
    const float* i1 = ir + base;
    const float* i2 = X + base;
    const float* i3 = Y + base;

    // register pipeline: rows y-1, y, y+1 for each of the 4 images
    Row6 a0 = load_row(i0, y0 - 1, x0), a1 = load_row(i0, y0, x0), a2;
    Row6 b0 = load_row(i1, y0 - 1, x0), b1 = load_row(i1, y0, x0), b2;
    Row6 c0 = load_row(i2, y0 - 1, x0), c1 = load_row(i2, y0, x0), c2;
    Row6 d0 = load_row(i3, y0 - 1, x0), d1 = load_row(i3, y0, x0), d2;

    float sX2 = 0.f, sY2 = 0.f, sL1 = 0.f;

    #pragma unroll
    for (int k = 0; k < TH; ++k) {
        const int yin = y0 + k + 1;
        a2 = load_row(i0, yin, x0);
        b2 = load_row(i1, yin, x0);
        c2 = load_row(i2, yin, x0);
        d2 = load_row(i3, yin, x0);

        #pragma unroll
        for (int j = 0; j < 4; ++j) {
            float gv = sob(a0, a1, a2, j);
            float gi = sob(b0, b1, b2, j);
            float gX = sob(c0, c1, c2, j);
            float gY = sob(d0, d1, d2, j);
            sX2 += gX * gX;
            sY2 += gY * gY;
            sL1 += fabsf(gX - fmaxf(gv, gi));
        }

        a0 = a1; a1 = a2;
        b0 = b1; b1 = b2;
        c0 = c1; c1 = c2;
        d0 = d1; d1 = d2;
    }

    // wave reduce (64 lanes), then 3-wave LDS reduce
    #pragma unroll
    for (int off = 32; off > 0; off >>= 1) {
        sX2 += __shfl_down(sX2, off);
        sY2 += __shfl_down(sY2, off);
        sL1 += __shfl_down(sL1, off);
    }
    const int wave = tid >> 6;
    const int lane = tid & 63;
    if (lane == 0) { red[0][wave] = sX2; red[1][wave] = sY2; red[2][wave] = sL1; }
    __syncthreads();
    if (tid == 0) {
        part[0 * NBLOCKS + bid] = red[0][0] + red[0][1] + red[0][2];
        part[1 * NBLOCKS + bid] = red[1][0] + red[1][1] + red[1][2];
        part[2 * NBLOCKS + bid] = red[2][0] + red[2][1] + red[2][2];
    }
}

__global__ __launch_bounds__(1024) void reduce_finalize(
    const float* __restrict__ part, float* __restrict__ out)
{
    __shared__ float red[3][16];
    const int tid = threadIdx.x;

    float a = 0.f, b = 0.f, c = 0.f;
    for (int i = tid; i < NBLOCKS; i += 1024) {
        a += part[0 * NBLOCKS + i];
        b += part[1 * NBLOCKS + i];
        c += part[2 * NBLOCKS + i];
    }
    #pragma unroll
    for (int off = 32; off > 0; off >>= 1) {
        a += __shfl_down(a, off);
        b += __shfl_down(b, off);
        c += __shfl_down(c, off);
    }
    const int wave = tid >> 6;
    const int lane = tid & 63;
    if (lane == 0) { red[0][wave] = a; red[1][wave] = b; red[2][wave] = c; }
    __syncthreads();
    if (tid == 0) {
        float sa = 0.f, sb = 0.f, sc = 0.f;
        #pragma unroll
        for (int w = 0; w < 16; ++w) { sa += red[0][w]; sb += red[1][w]; sc += red[2][w]; }
        out[0] = sb / sa;                      // loss_in = sumY2 / sumX2
        out[1] = sc * (1.f / (float)NPIX);     // loss_grad = sumL1 / N
    }
}

extern "C" void kernel_launch(void* const* d_in, const int* in_sizes, int n_in,
                              void* d_out, int out_size, void* d_ws, size_t ws_size,
                              hipStream_t stream) {
    const float* vis = (const float*)d_in[0];
    const float* ir  = (const float*)d_in[1];
    const float* X   = (const float*)d_in[2];
    const float* Y   = (const float*)d_in[3];
    float* out = (float*)d_out;
    float* part = (float*)d_ws;   // 3 * NBLOCKS floats = 12 KB

    dim3 grid(NSTRIPS, BATCH);    // 64 x 16 = 1024 blocks
    sobel_loss_main<<<grid, TPB, 0, stream>>>(vis, ir, X, Y, part);
    reduce_finalize<<<1, 1024, 0, stream>>>(part, out);
}

// Round 4
// 40.986 us; speedup vs baseline: 9.0955x; 1.1708x over previous
//
#include <hip/hip_runtime.h>
#include <math.h>

#define IMG_H 768
#define IMG_W 768
#define BATCH 16
#define TH 6                       // output rows per block
#define TPB 192                    // threads per block = 768/4 (3 waves)
#define NSTRIPS (IMG_H / TH)       // 128
#define NBLOCKS (NSTRIPS * BATCH)  // 2048
#define NPIX ((size_t)BATCH * IMG_H * IMG_W)  // 9437184

struct Row6 { float v[6]; };       // x0-1 .. x0+4

__device__ __forceinline__ Row6 load_row(const float* __restrict__ img, int row, int x0) {
    Row6 r;
    if (row < 0 || row >= IMG_H) {
        #pragma unroll
        for (int i = 0; i < 6; ++i) r.v[i] = 0.f;
        return r;
    }
    const float* p = img + row * IMG_W + x0;
    float4 m = *(const float4*)p;                 // 16B-aligned (x0 % 4 == 0)
    r.v[0] = (x0 > 0) ? p[-1] : 0.f;
    r.v[1] = m.x; r.v[2] = m.y; r.v[3] = m.z; r.v[4] = m.w;
    r.v[5] = (x0 + 4 < IMG_W) ? p[4] : 0.f;
    return r;
}

// sobel |gx|+|gy| at output offset j (0..3) from 3 register rows
__device__ __forceinline__ float sob(const Row6& r0, const Row6& r1, const Row6& r2, int j) {
    float gx = (r0.v[j + 2] - r0.v[j]) + 2.f * (r1.v[j + 2] - r1.v[j]) + (r2.v[j + 2] - r2.v[j]);
    float gy = (r0.v[j] - r2.v[j]) + 2.f * (r0.v[j + 1] - r2.v[j + 1]) + (r0.v[j + 2] - r2.v[j + 2]);
    return fabsf(gx) + fabsf(gy);
}

__global__ __launch_bounds__(TPB, 4) void sobel_loss_main(
    const float* __restrict__ vis, const float* __restrict__ ir,
    const float* __restrict__ X, const float* __restrict__ Y,
    float* __restrict__ part)   // part: [3][NBLOCKS]
{
    __shared__ float red[3][3];

    const int tid = threadIdx.x;
    const int x0 = tid * 4;
    const int y0 = blockIdx.x * TH;
    const size_t base = (size_t)blockIdx.y * (IMG_H * IMG_W);
    const int bid = blockIdx.y * NSTRIPS + blockIdx.x;

    const float* i0 = vis + base;
    const float* i1 = ir + base;
    const float* i2 = X + base;
    const float* i3 = Y + base;

    // register pipeline: rows y-1, y, y+1 for each of the 4 images
    Row6 a0 = load_row(i0, y0 - 1, x0), a1 = load_row(i0, y0, x0), a2;
    Row6 b0 = load_row(i1, y0 - 1, x0), b1 = load_row(i1, y0, x0), b2;
    Row6 c0 = load_row(i2, y0 - 1, x0), c1 = load_row(i2, y0, x0), c2;
    Row6 d0 = load_row(i3, y0 - 1, x0), d1 = load_row(i3, y0, x0), d2;

    float sX2 = 0.f, sY2 = 0.f, sL1 = 0.f;

    #pragma unroll 1
    for (int k = 0; k < TH; ++k) {
        const int yin = y0 + k + 1;
        a2 = load_row(i0, yin, x0);
        b2 = load_row(i1, yin, x0);
        c2 = load_row(i2, yin, x0);
        d2 = load_row(i3, yin, x0);

        #pragma unroll
        for (int j = 0; j < 4; ++j) {
            float gv = sob(a0, a1, a2, j);
            float gi = sob(b0, b1, b2, j);
            float gX = sob(c0, c1, c2, j);
            float gY = sob(d0, d1, d2, j);
            sX2 += gX * gX;
            sY2 += gY * gY;
            sL1 += fabsf(gX - fmaxf(gv, gi));
        }

        a0 = a1; a1 = a2;
        b0 = b1; b1 = b2;
        c0 = c1; c1 = c2;
        d0 = d1; d1 = d2;
    }

    // wave reduce (64 lanes), then 3-wave LDS reduce
    #pragma unroll
    for (int off = 32; off > 0; off >>= 1) {
        sX2 += __shfl_down(sX2, off);
        sY2 += __shfl_down(sY2, off);
        sL1 += __shfl_down(sL1, off);
    }
    const int wave = tid >> 6;
    const int lane = tid & 63;
    if (lane == 0) { red[0][wave] = sX2; red[1][wave] = sY2; red[2][wave] = sL1; }
    __syncthreads();
    if (tid == 0) {
        part[0 * NBLOCKS + bid] = red[0][0] + red[0][1] + red[0][2];
        part[1 * NBLOCKS + bid] = red[1][0] + red[1][1] + red[1][2];
        part[2 * NBLOCKS + bid] = red[2][0] + red[2][1] + red[2][2];
    }
}

__global__ __launch_bounds__(1024) void reduce_finalize(
    const float* __restrict__ part, float* __restrict__ out)
{
    __shared__ float red[3][16];
    const int tid = threadIdx.x;

    float a = 0.f, b = 0.f, c = 0.f;
    for (int i = tid; i < NBLOCKS; i += 1024) {
        a += part[0 * NBLOCKS + i];
        b += part[1 * NBLOCKS + i];
        c += part[2 * NBLOCKS + i];
    }
    #pragma unroll
    for (int off = 32; off > 0; off >>= 1) {
        a += __shfl_down(a, off);
        b += __shfl_down(b, off);
        c += __shfl_down(c, off);
    }
    const int wave = tid >> 6;
    const int lane = tid & 63;
    if (lane == 0) { red[0][wave] = a; red[1][wave] = b; red[2][wave] = c; }
    __syncthreads();
    if (tid == 0) {
        float sa = 0.f, sb = 0.f, sc = 0.f;
        #pragma unroll
        for (int w = 0; w < 16; ++w) { sa += red[0][w]; sb += red[1][w]; sc += red[2][w]; }
        out[0] = sb / sa;                      // loss_in = sumY2 / sumX2
        out[1] = sc * (1.f / (float)NPIX);     // loss_grad = sumL1 / N
    }
}

extern "C" void kernel_launch(void* const* d_in, const int* in_sizes, int n_in,
                              void* d_out, int out_size, void* d_ws, size_t ws_size,
                              hipStream_t stream) {
    const float* vis = (const float*)d_in[0];
    const float* ir  = (const float*)d_in[1];
    const float* X   = (const float*)d_in[2];
    const float* Y   = (const float*)d_in[3];
    float* out = (float*)d_out;
    float* part = (float*)d_ws;   // 3 * NBLOCKS floats = 24 KB

    dim3 grid(NSTRIPS, BATCH);    // 128 x 16 = 2048 blocks
    sobel_loss_main<<<grid, TPB, 0, stream>>>(vis, ir, X, Y, part);
    reduce_finalize<<<1, 1024, 0, stream>>>(part, out);
}